// Round 5
// baseline (15.479 us; speedup 1.0000x reference)
//
#include <hip/hip_runtime.h>

namespace {

constexpr int B_ = 4, C_ = 64, H_ = 96, W_ = 192, S_ = 12;
constexpr int HW = H_ * W_;
constexpr float TEMP_OVER_C = 7.0f / 64.0f;   // TEMPERATURE / C
constexpr int OUT_HALF = B_ * 4 * H_ * W_;    // ndisp_out first, then disp_out
constexpr int LSTR = 68;                      // LDS row stride: 68%32=4 -> bank spread, 16B-aligned rows
constexpr int CNT = 144;                      // staged columns (uniform for both halves)

__global__ __launch_bounds__(192) void fused_eval(
    const float* __restrict__ left, const float* __restrict__ right,
    const float* __restrict__ disp, const float* __restrict__ ndisp,
    float* __restrict__ out)
{
  __shared__ float rlds[CNT * LSTR];   // 39168 B -> 4 blocks/CU resident

  // grid 768: bid and bid+384 are the two halves of one (b,h) row.
  const int bid = blockIdx.x;
  const int half = (bid >= 384) ? 1 : 0;
  const int bh = bid - half * 384;
  const int b = bh / H_;
  const int h = bh - b * H_;
  const int w0 = half * 96;
  const int s0g = half * 48;              // staged right columns [s0g, s0g+144)

  const int t = threadIdx.x;              // 0..191
  const int shalf = (t >= 96) ? 1 : 0;    // sample half: s 0..5 or 6..11
  const int wl = t - shalf * 96;          // 0..95
  const int w = w0 + wl;

  // ---- issue the FULL left preload first: latency hides under staging+barrier,
  //      post-barrier dot phase has no global dependencies ----
  const float* lcol = left + (size_t)b * C_ * HW + (size_t)h * W_ + w;
  float la[64];
  #pragma unroll
  for (int c = 0; c < 64; ++c) la[c] = lcol[(size_t)c * HW];

  // ---- stage right[b, :, h, s0g:s0g+144) transposed into LDS [col][chan] ----
  // 576 tasks = 144 cols x 4 chan-groups; 3 tasks/thread, all threads busy.
  // Reads coalesced across col; b128 writes at stride-68 are bank-balanced.
  const float* rrow = right + (size_t)b * C_ * HW + (size_t)h * W_ + s0g;
  #pragma unroll
  for (int k = 0; k < 3; ++k) {
    const int task = t + 192 * k;
    const int col = task % CNT;
    const int cg  = task / CNT;           // 0..3
    const float* src = rrow + (size_t)(cg * 16) * HW + col;
    float v[16];
    #pragma unroll
    for (int j = 0; j < 16; ++j) v[j] = src[(size_t)j * HW];
    float* dst = &rlds[col * LSTR + cg * 16];
    #pragma unroll
    for (int j = 0; j < 4; ++j)
      *reinterpret_cast<float4*>(dst + 4 * j) =
          make_float4(v[4 * j], v[4 * j + 1], v[4 * j + 2], v[4 * j + 3]);
  }

  // ---- sample setup (disp needed for idx before barrier) ----
  const int sb = 6 * shalf;
  float dsp[6]; int jdx[6];
  const size_t dbase = ((size_t)(b * S_ + sb) * H_ + h) * W_ + w;
  #pragma unroll
  for (int s = 0; s < 6; ++s) {
    dsp[s] = disp[dbase + (size_t)s * HW];
    // reference: clip(w - d, 0, W-1) in f32, then int32 truncation
    const float ry = fminf(fmaxf((float)w - dsp[s], 0.0f), (float)(W_ - 1));
    jdx[s] = (int)ry - s0g;
  }

  __syncthreads();

  // ndisp only needed in epilogue: issue now, latency hides under the gather
  float nds[6];
  #pragma unroll
  for (int s = 0; s < 6; ++s) nds[s] = ndisp[dbase + (size_t)s * HW];

  // ---- pure-LDS dot phase: 6 samples x 64 channels, b128 gathers ----
  const float* rp[6];
  #pragma unroll
  for (int s = 0; s < 6; ++s) rp[s] = &rlds[jdx[s] * LSTR];

  float st[6] = {0.f, 0.f, 0.f, 0.f, 0.f, 0.f};
  #pragma unroll
  for (int cg = 0; cg < 4; ++cg) {
    #pragma unroll
    for (int s = 0; s < 6; ++s) {
      const float* rr = rp[s] + cg * 16;
      const float4 r0 = *reinterpret_cast<const float4*>(rr);
      const float4 r1 = *reinterpret_cast<const float4*>(rr + 4);
      const float4 r2 = *reinterpret_cast<const float4*>(rr + 8);
      const float4 r3 = *reinterpret_cast<const float4*>(rr + 12);
      float a = st[s];
      a = fmaf(la[cg*16+ 0], r0.x, a);  a = fmaf(la[cg*16+ 1], r0.y, a);
      a = fmaf(la[cg*16+ 2], r0.z, a);  a = fmaf(la[cg*16+ 3], r0.w, a);
      a = fmaf(la[cg*16+ 4], r1.x, a);  a = fmaf(la[cg*16+ 5], r1.y, a);
      a = fmaf(la[cg*16+ 6], r1.z, a);  a = fmaf(la[cg*16+ 7], r1.w, a);
      a = fmaf(la[cg*16+ 8], r2.x, a);  a = fmaf(la[cg*16+ 9], r2.y, a);
      a = fmaf(la[cg*16+10], r2.z, a);  a = fmaf(la[cg*16+11], r2.w, a);
      a = fmaf(la[cg*16+12], r3.x, a);  a = fmaf(la[cg*16+13], r3.y, a);
      a = fmaf(la[cg*16+14], r3.z, a);  a = fmaf(la[cg*16+15], r3.w, a);
      st[s] = a;
    }
  }

  // ---- epilogue: 2 intervals per thread, fully static ----
  #pragma unroll
  for (int ii = 0; ii < 2; ++ii) {
    const float a0 = st[3 * ii + 0] * TEMP_OVER_C;
    const float a1 = st[3 * ii + 1] * TEMP_OVER_C;
    const float a2 = st[3 * ii + 2] * TEMP_OVER_C;
    const float m  = fmaxf(a0, fmaxf(a1, a2));
    const float e0 = __expf(a0 - m);
    const float e1 = __expf(a1 - m);
    const float e2 = __expf(a2 - m);
    const float inv = 1.0f / (e0 + e1 + e2);
    const int iv = 2 * shalf + ii;
    const size_t o = ((size_t)(b * 4 + iv) * H_ + h) * W_ + w;
    out[o] = (nds[3 * ii] * e0 + nds[3 * ii + 1] * e1 + nds[3 * ii + 2] * e2) * inv;
    out[OUT_HALF + o] =
        (dsp[3 * ii] * e0 + dsp[3 * ii + 1] * e1 + dsp[3 * ii + 2] * e2) * inv;
  }
}

} // namespace

extern "C" void kernel_launch(void* const* d_in, const int* in_sizes, int n_in,
                              void* d_out, int out_size, void* d_ws, size_t ws_size,
                              hipStream_t stream) {
  const float* left  = (const float*)d_in[0];
  const float* right = (const float*)d_in[1];
  const float* disp  = (const float*)d_in[2];
  const float* ndisp = (const float*)d_in[3];
  float* out = (float*)d_out;
  dim3 grid(2 * B_ * H_);
  dim3 block(192);
  hipLaunchKernelGGL(fused_eval, grid, block, 0, stream, left, right, disp, ndisp, out);
}

// Round 6
// 14.723 us; speedup vs baseline: 1.0514x; 1.0514x over previous
//
#include <hip/hip_runtime.h>

namespace {

constexpr int B_ = 4, C_ = 64, H_ = 96, W_ = 192, S_ = 12;
constexpr int HW = H_ * W_;
constexpr float TEMP_OVER_C = 7.0f / 64.0f;   // TEMPERATURE / C
constexpr int OUT_HALF = B_ * 4 * H_ * W_;    // ndisp_out first, then disp_out
constexpr int LSTR = 68;                      // LDS stride: 68%32=4 -> b128 lanes tile banks conflict-free

#define GATHER_CHUNK(LR, C0)                                              \
  {                                                                       \
    _Pragma("unroll")                                                     \
    for (int s = 0; s < 6; ++s) {                                         \
      const float* rr = rp[s] + (C0);                                     \
      const float4 r0 = *reinterpret_cast<const float4*>(rr);             \
      const float4 r1 = *reinterpret_cast<const float4*>(rr + 4);         \
      const float4 r2 = *reinterpret_cast<const float4*>(rr + 8);         \
      const float4 r3 = *reinterpret_cast<const float4*>(rr + 12);        \
      float a = st[s];                                                    \
      a = fmaf(LR[0],  r0.x, a);  a = fmaf(LR[1],  r0.y, a);              \
      a = fmaf(LR[2],  r0.z, a);  a = fmaf(LR[3],  r0.w, a);              \
      a = fmaf(LR[4],  r1.x, a);  a = fmaf(LR[5],  r1.y, a);              \
      a = fmaf(LR[6],  r1.z, a);  a = fmaf(LR[7],  r1.w, a);              \
      a = fmaf(LR[8],  r2.x, a);  a = fmaf(LR[9],  r2.y, a);              \
      a = fmaf(LR[10], r2.z, a);  a = fmaf(LR[11], r2.w, a);              \
      a = fmaf(LR[12], r3.x, a);  a = fmaf(LR[13], r3.y, a);              \
      a = fmaf(LR[14], r3.z, a);  a = fmaf(LR[15], r3.w, a);              \
      st[s] = a;                                                          \
    }                                                                     \
  }

__global__ __launch_bounds__(192) void fused_eval(
    const float* __restrict__ left, const float* __restrict__ right,
    const float* __restrict__ disp, const float* __restrict__ ndisp,
    float* __restrict__ out)
{
  __shared__ float rlds[144 * LSTR];   // 39168 B

  // grid 768: bid and bid+384 are the two halves of one (b,h) row;
  // 384 % 8 == 0 -> pair lands on the same XCD (halo cols hit L2).
  const int bid = blockIdx.x;
  const int half = (bid >= 384) ? 1 : 0;
  const int bh = bid - half * 384;
  const int b = bh / H_;
  const int h = bh - b * H_;
  const int w0 = half * 96;
  const int s0g = half * 48;              // staged right cols: [s0g, s0g + (96|144))

  const int t = threadIdx.x;              // 0..191
  const int shalf = (t >= 96) ? 1 : 0;    // sample half: s 0..5 or 6..11
  const int wl = t - shalf * 96;          // 0..95
  const int w = w0 + wl;

  // ---- STAGING READS FIRST (they gate the barrier) ----
  // part A (both halves): local cols 0..95; thread stages col=wl,
  // channels [32*shalf, 32*shalf+32) -> 32 coalesced scalar reads
  const float* rrow = right + (size_t)b * C_ * HW + (size_t)h * W_ + s0g;
  const int cbA = shalf * 32;
  float va[32];
  {
    const float* srcA = rrow + wl;
    #pragma unroll
    for (int j = 0; j < 32; ++j) va[j] = srcA[(size_t)(cbA + j) * HW];
  }
  // part B (half 1 only, uniform branch): local cols 96..143, 4 chan-groups;
  // 192 tasks, 1/thread -> 16 coalesced scalar reads
  float vb[16];
  int colB = 96, cbB = 0;
  if (half) {
    const int cgB = t / 48;               // 0..3 (const-divisor magic mul)
    colB = 96 + (t - cgB * 48);
    cbB = cgB * 16;
    const float* srcB = rrow + colB;
    #pragma unroll
    for (int j = 0; j < 16; ++j) vb[j] = srcB[(size_t)(cbB + j) * HW];
  }

  // ---- sample setup (disp needed for idx; issue behind staging reads) ----
  const int sb = 6 * shalf;
  float dsp[6]; int jdx[6];
  const size_t dbase = ((size_t)(b * S_ + sb) * H_ + h) * W_ + w;
  #pragma unroll
  for (int s = 0; s < 6; ++s) {
    dsp[s] = disp[dbase + (size_t)s * HW];
    // reference: clip(w - d, 0, W-1) in f32, then int32 truncation
    const float ry = fminf(fmaxf((float)w - dsp[s], 0.0f), (float)(W_ - 1));
    jdx[s] = (int)ry - s0g;
  }

  // left chunk 0 (c 0..15): latency hides under staging writes + barrier
  const float* lcol = left + (size_t)b * C_ * HW + (size_t)h * W_ + w;
  float la[16], lb[16];
  #pragma unroll
  for (int c = 0; c < 16; ++c) la[c] = lcol[(size_t)c * HW];

  // ---- LDS writes (transposed [col][chan], b128, bank-conflict-free) ----
  {
    float* dstA = &rlds[wl * LSTR + cbA];
    #pragma unroll
    for (int j = 0; j < 8; ++j)
      *reinterpret_cast<float4*>(dstA + 4 * j) =
          make_float4(va[4*j], va[4*j+1], va[4*j+2], va[4*j+3]);
  }
  if (half) {
    float* dstB = &rlds[colB * LSTR + cbB];
    #pragma unroll
    for (int j = 0; j < 4; ++j)
      *reinterpret_cast<float4*>(dstB + 4 * j) =
          make_float4(vb[4*j], vb[4*j+1], vb[4*j+2], vb[4*j+3]);
  }

  __syncthreads();

  // ndisp only needed in epilogue: issue now, latency hides under gather
  float nds[6];
  #pragma unroll
  for (int s = 0; s < 6; ++s) nds[s] = ndisp[dbase + (size_t)s * HW];

  // ---- gather phase: pure LDS + FMA, left chunks pipelined via VMEM ----
  const float* rp[6];
  #pragma unroll
  for (int s = 0; s < 6; ++s) rp[s] = &rlds[jdx[s] * LSTR];

  float st[6] = {0.f, 0.f, 0.f, 0.f, 0.f, 0.f};

  #pragma unroll
  for (int c = 0; c < 16; ++c) lb[c] = lcol[(size_t)(16 + c) * HW];
  GATHER_CHUNK(la, 0)
  #pragma unroll
  for (int c = 0; c < 16; ++c) la[c] = lcol[(size_t)(32 + c) * HW];
  GATHER_CHUNK(lb, 16)
  #pragma unroll
  for (int c = 0; c < 16; ++c) lb[c] = lcol[(size_t)(48 + c) * HW];
  GATHER_CHUNK(la, 32)
  GATHER_CHUNK(lb, 48)

  // ---- epilogue: 2 intervals per thread, fully static ----
  #pragma unroll
  for (int ii = 0; ii < 2; ++ii) {
    const float a0 = st[3 * ii + 0] * TEMP_OVER_C;
    const float a1 = st[3 * ii + 1] * TEMP_OVER_C;
    const float a2 = st[3 * ii + 2] * TEMP_OVER_C;
    const float m  = fmaxf(a0, fmaxf(a1, a2));
    const float e0 = __expf(a0 - m);
    const float e1 = __expf(a1 - m);
    const float e2 = __expf(a2 - m);
    const float inv = 1.0f / (e0 + e1 + e2);
    const int iv = 2 * shalf + ii;
    const size_t o = ((size_t)(b * 4 + iv) * H_ + h) * W_ + w;
    out[o] = (nds[3 * ii] * e0 + nds[3 * ii + 1] * e1 + nds[3 * ii + 2] * e2) * inv;
    out[OUT_HALF + o] =
        (dsp[3 * ii] * e0 + dsp[3 * ii + 1] * e1 + dsp[3 * ii + 2] * e2) * inv;
  }
}

} // namespace

extern "C" void kernel_launch(void* const* d_in, const int* in_sizes, int n_in,
                              void* d_out, int out_size, void* d_ws, size_t ws_size,
                              hipStream_t stream) {
  const float* left  = (const float*)d_in[0];
  const float* right = (const float*)d_in[1];
  const float* disp  = (const float*)d_in[2];
  const float* ndisp = (const float*)d_in[3];
  float* out = (float*)d_out;
  dim3 grid(2 * B_ * H_);
  dim3 block(192);
  hipLaunchKernelGGL(fused_eval, grid, block, 0, stream, left, right, disp, ndisp, out);
}